// Round 12
// baseline (100.956 us; speedup 1.0000x reference)
//
#include <hip/hip_runtime.h>
#include <hip/hip_bf16.h>

using bf16 = __hip_bfloat16;
typedef __attribute__((ext_vector_type(8))) short frag_ab;   // 8 bf16
typedef __attribute__((ext_vector_type(4))) float frag_cd;   // 4 fp32

constexpr float TEMP   = 0.07f;
constexpr float INVT   = 1.0f / TEMP;                 // fixed logsumexp shift
constexpr float THRESH = 0.1f;
constexpr float EPS    = 1e-8f;
constexpr float LOG2E  = 1.4426950408889634f;
constexpr float C1     = LOG2E / TEMP;                // exp((s-1)/T) = exp2(s*C1 - C1)

constexpr int D  = 128;
constexpr int TC = 128;   // tile size (rows and cols): block (R,C) does a 128x128 tile

__device__ __forceinline__ frag_cd mfma16(frag_ab a, frag_ab b, frag_cd c) {
    return __builtin_amdgcn_mfma_f32_16x16x32_bf16(a, b, c, 0, 0, 0);
}

// async global->LDS DMA, 16B per lane, LDS dest = wave-uniform base + lane*16
__device__ __forceinline__ void async_copy16(const bf16* gp, bf16* lp) {
    __builtin_amdgcn_global_load_lds(
        (__attribute__((address_space(1))) void*)(gp),
        (__attribute__((address_space(3))) void*)(lp), 16, 0, 0);
}

// ------- kernel 1: row-normalize -> bf16, diagonal dot, LABEL-ONLY positive count -------
// cnt_i = #{j : |l_i - l_j| < THRESH} - 1 depends only on labels — no sim needed.
// Exact integer sums in f32 (<= 8192), any order => bit-identical to the masked count.
// Removing cnt from k2 saves ~12 VGPRs, 2 VALU/elem, and a 2 MB partial array.
__global__ __launch_bounds__(256) void k1_normalize(
    const float* __restrict__ f, const float* __restrict__ lab,
    bf16* __restrict__ fn, float* __restrict__ diag,
    float* __restrict__ cnt_g, float* __restrict__ acc,
    unsigned* __restrict__ counter, int n)
{
    if (blockIdx.x == 0 && threadIdx.x == 0) { acc[0] = 0.f; counter[0] = 0u; }
    const int row  = blockIdx.x * 4 + (threadIdx.x >> 6);
    const int lane = threadIdx.x & 63;
    float2 v = ((const float2*)(f + (size_t)row * D))[lane];
    float ss = v.x * v.x + v.y * v.y;
    #pragma unroll
    for (int m = 32; m >= 1; m >>= 1) ss += __shfl_xor(ss, m, 64);
    const float inv = 1.0f / fmaxf(sqrtf(ss), EPS);
    __hip_bfloat162 o;
    o.x = __float2bfloat16(v.x * inv);
    o.y = __float2bfloat16(v.y * inv);
    ((__hip_bfloat162*)(fn + (size_t)row * D))[lane] = o;
    // diagonal raw dot of the bf16-rounded row (matches MFMA s_ii to ~1e-6)
    const float a = __bfloat162float(o.x), b = __bfloat162float(o.y);
    float p = a * a + b * b;
    #pragma unroll
    for (int m = 32; m >= 1; m >>= 1) p += __shfl_xor(p, m, 64);
    if (lane == 0) diag[row] = p;

    // label-only count (labels are L1/L2-resident after the first blocks)
    const float li = lab[row];
    float c = 0.f;
    const int it = n >> 8;                   // n/256 float4-iters per lane
    for (int k = 0; k < it; ++k) {
        const float4 lv = ((const float4*)lab)[lane + 64 * k];
        c += (fabsf(lv.x - li) < THRESH) ? 1.f : 0.f;
        c += (fabsf(lv.y - li) < THRESH) ? 1.f : 0.f;
        c += (fabsf(lv.z - li) < THRESH) ? 1.f : 0.f;
        c += (fabsf(lv.w - li) < THRESH) ? 1.f : 0.f;
    }
    #pragma unroll
    for (int m = 32; m >= 1; m >>= 1) c += __shfl_xor(c, m, 64);
    if (lane == 0) cnt_g[row] = c - 1.0f;    // exclude self
}

// ---------------- kernel 2: SYMMETRIC fused sim + masked reductions ----------------
// Upper triangle of 128x128 tiles (2080 blocks). Block (R,C), C>=R, credits both
// endpoints via disjoint partial-split slots (R8/R10-verified, absmax 0):
//   row-side -> split C, rows in R ; col-side -> split R, rows in C (off-diag only).
//
// R10 post-mortem: private ds_writes fixed the in-loop stall but the 26 KB csum
// pushed LDS to 59 KB -> 2 blocks/CU, halving latency-hiding; k2 stayed ~40 us.
// This round: csum LDS = ZERO. Col partials live in 8 registers per 4-sub half and
// are dumped into the DEAD half of colbuf (cols 0-63 storage is never read after
// all waves pass sub 3; cols 64-127 after sub 7). Two extra barriers; writes are
// private fire-and-forget. LDS 32.75 KB -> 4 blocks/CU restored. cnt removed
// entirely (label-only, k1). VGPR ~110 < 128 cap.
// LAUNCH-BOUNDS LAW (R0/R2/R4/R7): cap = 256/min_waves -> (256,2). DO NOT RAISE.
__global__ __launch_bounds__(256, 2) void k2_main(
    const bf16* __restrict__ fn, const float* __restrict__ lab,
    float* __restrict__ se_p, float* __restrict__ sp_p,
    int n, int nb)
{
    // linear triangle decode: bid -> (Rb, Cb), 0 <= Rb <= Cb < nb
    const int bid = blockIdx.x;
    int Rb = (int)floorf(((2.0f * nb + 1.0f)
              - sqrtf((2.0f * nb + 1.0f) * (2.0f * nb + 1.0f) - 8.0f * (float)bid)) * 0.5f);
    while ((Rb + 1) * (2 * nb - Rb) / 2 <= bid) ++Rb;       // f32 decode correction
    while (Rb * (2 * nb - Rb + 1) / 2 > bid) --Rb;
    const int Cb = Rb + (bid - Rb * (2 * nb - Rb + 1) / 2);
    const bool diagblk = (Cb == Rb);

    __shared__ __align__(16) char smem[TC * D * sizeof(bf16)];  // 32 KB colbuf
    __shared__ float lab_s[TC];
    bf16*  colbuf = (bf16*)smem;
    float* ovA = (float*)smem;               // [2][16][64] = 8 KB, cols 0-63 region (dead after bar2)
    float* ovB = (float*)(smem + 16384);     // [2][16][64] = 8 KB, cols 64-127 region (dead after bar3)

    const int tid  = threadIdx.x;
    const int wave = tid >> 6;
    const int lane = tid & 63;
    const int quad = lane >> 4;
    const int l15  = lane & 15;
    const int wq   = wave * 4 + quad;

    const int row_base = Rb * TC + wave * 32;
    const int col_base = Cb * TC;

    if (tid < TC) lab_s[tid] = lab[col_base + tid];

    // DMA the col tile: 8 issues/wave, issue i lane l -> LDS byte wave*8192+i*1024+l*16
    //   col ci = wave*32 + i*4 + (l>>4), slot l&15, source chunk = l15 ^ (ci&15)
    {
        const bf16* gt = fn + (size_t)col_base * D;
        bf16* lb = colbuf + wave * 4096;
        #pragma unroll
        for (int i = 0; i < 8; ++i) {
            const int ci = wave * 32 + i * 4 + (lane >> 4);
            const int ki = l15 ^ (ci & 15);
            async_copy16(gt + (size_t)ci * D + ki * 8, lb + i * 512);
        }
    }

    // A fragments (overlap the DMA): set s covers rows row_base+s*16+l15, k=kb*32+quad*8+j
    frag_ab afr[2][4];
    #pragma unroll
    for (int s = 0; s < 2; ++s) {
        const bf16* ap = fn + (size_t)(row_base + s * 16 + l15) * D + quad * 8;
        #pragma unroll
        for (int kb = 0; kb < 4; ++kb) afr[s][kb] = *(const frag_ab*)(ap + kb * 32);
    }
    float li[2][4];
    #pragma unroll
    for (int s = 0; s < 2; ++s)
        #pragma unroll
        for (int r = 0; r < 4; ++r)
            li[s][r] = lab[row_base + s * 16 + quad * 4 + r];

    float se[2][4] = {}, sp[2][4] = {};
    float cs_e[4], cs_sp[4];                 // col-side partials for the current 4-sub half

    __syncthreads();   // bar1: DMA drained (vmcnt0 before s_barrier); colbuf + lab_s ready

    // one 16-col sub: 4 ds_read_b128, 8 MFMA, epilogue; col partials -> registers only
    #define DO_SUB(SUB, HALFIDX)                                                          \
    {                                                                                     \
        const int c = (SUB) * 16 + l15;                                                   \
        frag_ab b[4];                                                                     \
        _Pragma("unroll")                                                                 \
        for (int kb = 0; kb < 4; ++kb)                                                    \
            b[kb] = *(const frag_ab*)(&colbuf[(size_t)c * D + (((quad + 4 * kb) ^ l15) * 8)]); \
        frag_cd a0 = {0.f,0.f,0.f,0.f}, a1 = {0.f,0.f,0.f,0.f};                           \
        _Pragma("unroll")                                                                 \
        for (int kb = 0; kb < 4; ++kb) {                                                  \
            a0 = mfma16(afr[0][kb], b[kb], a0);                                           \
            a1 = mfma16(afr[1][kb], b[kb], a1);                                           \
        }                                                                                 \
        const float lj = lab_s[c];                                                        \
        float ce = 0.f, cp = 0.f;                                                         \
        _Pragma("unroll")                                                                 \
        for (int s = 0; s < 2; ++s) {                                                     \
            const frag_cd& acc = s ? a1 : a0;                                             \
            _Pragma("unroll")                                                             \
            for (int r = 0; r < 4; ++r) {                                                 \
                const float sv = acc[r];                                                  \
                const float e  = __builtin_amdgcn_exp2f(__builtin_fmaf(sv, C1, -C1));     \
                const float pm = (fabsf(li[s][r] - lj) < THRESH) ? 1.0f : 0.0f;           \
                se[s][r] += e;                                                            \
                sp[s][r]  = __builtin_fmaf(pm, sv, sp[s][r]);                             \
                ce += e;                                                                  \
                cp  = __builtin_fmaf(pm, sv, cp);                                         \
            }                                                                             \
        }                                                                                 \
        cs_e[HALFIDX] = ce; cs_sp[HALFIDX] = cp;                                          \
    }

    DO_SUB(0, 0) DO_SUB(1, 1) DO_SUB(2, 2) DO_SUB(3, 3)

    __syncthreads();   // bar2: ALL waves done reading cols 0-63 -> that 16 KB is scratch now
    if (!diagblk) {
        #pragma unroll
        for (int s4 = 0; s4 < 4; ++s4) {
            const int c = s4 * 16 + l15;                     // 0..63
            ovA[(0 * 16 + wq) * 64 + c] = cs_e[s4];          // private cells, fire-and-forget
            ovA[(1 * 16 + wq) * 64 + c] = cs_sp[s4];
        }
    }

    DO_SUB(4, 0) DO_SUB(5, 1) DO_SUB(6, 2) DO_SUB(7, 3)
    #undef DO_SUB

    __syncthreads();   // bar3: cols 64-127 reads done -> second 16 KB is scratch
    if (!diagblk) {
        #pragma unroll
        for (int s4 = 0; s4 < 4; ++s4) {
            const int c = s4 * 16 + l15;                     // col-64 index 0..63
            ovB[(0 * 16 + wq) * 64 + c] = cs_e[s4];
            ovB[(1 * 16 + wq) * 64 + c] = cs_sp[s4];
        }
    }

    // row-side: butterfly across the 16 lanes of each quad-group -> split Cb (plain stores)
    #pragma unroll
    for (int s = 0; s < 2; ++s)
        #pragma unroll
        for (int r = 0; r < 4; ++r) {
            #pragma unroll
            for (int m = 1; m < 16; m <<= 1) {
                se[s][r] += __shfl_xor(se[s][r], m, 64);
                sp[s][r] += __shfl_xor(sp[s][r], m, 64);
            }
        }
    if (l15 == 0) {
        #pragma unroll
        for (int s = 0; s < 2; ++s)
            #pragma unroll
            for (int r = 0; r < 4; ++r) {
                const int i = row_base + s * 16 + quad * 4 + r;
                se_p[(size_t)Cb * n + i] = se[s][r];
                sp_p[(size_t)Cb * n + i] = sp[s][r];
            }
    }

    // col-side combine -> split Rb (off-diag only; diagblk is block-uniform -> barriers safe)
    __syncthreads();   // bar4: ovA/ovB writes visible
    if (!diagblk && tid < TC) {
        const float* src = (tid < 64) ? ovA : ovB;
        const int c = tid & 63;
        float ve = 0.f, vs = 0.f;
        #pragma unroll
        for (int k = 0; k < 16; ++k) {
            ve += src[(0 * 16 + k) * 64 + c];
            vs += src[(1 * 16 + k) * 64 + c];
        }
        se_p[(size_t)Rb * n + col_base + tid] = ve;
        sp_p[(size_t)Rb * n + col_base + tid] = vs;
    }
}

// ------- kernel 3: per-row finalize (64 splits, wave-split + unrolled) + grid reduce -------
__global__ __launch_bounds__(256) void k3_finalize(
    const float* __restrict__ diag, const float* __restrict__ se_p,
    const float* __restrict__ sp_p, const float* __restrict__ cnt_g,
    float* __restrict__ acc, unsigned* __restrict__ counter,
    float* __restrict__ out, int n, int nb)
{
    const int tid  = threadIdx.x;
    const int wave = tid >> 6;
    const int lane = tid & 63;
    const int row  = blockIdx.x * 64 + lane;

    float se = 0.f, sp = 0.f;
    #pragma unroll
    for (int k = 0; k < 16; ++k) {
        const int s = wave * 16 + k;
        se += se_p[(size_t)s * n + row];
        sp += sp_p[(size_t)s * n + row];
    }
    __shared__ float part[2][4][64];
    part[0][wave][lane] = se;
    part[1][wave][lane] = sp;
    __syncthreads();
    if (wave == 0) {
        se = part[0][0][lane] + part[0][1][lane] + part[0][2][lane] + part[0][3][lane];
        sp = part[1][0][lane] + part[1][1][lane] + part[1][2][lane] + part[1][3][lane];
        const float s_ii = diag[row];
        se -= __builtin_amdgcn_exp2f(__builtin_fmaf(s_ii, C1, -C1));
        sp -= s_ii;
        const float cnt = cnt_g[row];        // label-only count, already excludes self
        float loss = INVT + __logf(se) - (sp * INVT) / fmaxf(cnt, 1.0f);
        #pragma unroll
        for (int m = 32; m >= 1; m >>= 1) loss += __shfl_xor(loss, m, 64);
        if (lane == 0) {
            atomicAdd(acc, loss);
            __threadfence();
            const unsigned old = atomicAdd(counter, 1u);
            if (old == gridDim.x - 1) {
                const float total = atomicAdd(acc, 0.0f);  // atomic load, same-address order
                out[0] = total / (float)n;
            }
        }
    }
}

extern "C" void kernel_launch(void* const* d_in, const int* in_sizes, int n_in,
                              void* d_out, int out_size, void* d_ws, size_t ws_size,
                              hipStream_t stream) {
    const float* feat = (const float*)d_in[0];
    const float* lab  = (const float*)d_in[1];
    const int n = in_sizes[1];              // 8192
    const int nb = n / TC;                  // 64 block-rows
    float* out = (float*)d_out;

    // ws: fn (n*D bf16 = 2MB) | diag (n f32) | se_p | sp_p (each nb*n f32 = 2MB)
    //     | cnt_g (n f32) | acc | counter
    char* ws = (char*)d_ws;
    bf16* fn = (bf16*)ws;
    size_t off = (size_t)n * D * sizeof(bf16);
    float* diag  = (float*)(ws + off); off += (size_t)n * sizeof(float);
    float* se_p  = (float*)(ws + off); off += (size_t)nb * n * sizeof(float);
    float* sp_p  = (float*)(ws + off); off += (size_t)nb * n * sizeof(float);
    float* cnt_g = (float*)(ws + off); off += (size_t)n * sizeof(float);
    float* acc   = (float*)(ws + off); off += sizeof(float);
    unsigned* counter = (unsigned*)(ws + off);

    k1_normalize<<<n / 4, 256, 0, stream>>>(feat, lab, fn, diag, cnt_g, acc, counter, n);
    const int ntri = nb * (nb + 1) / 2;     // 2080 live tiles
    k2_main<<<ntri, 256, 0, stream>>>(fn, lab, se_p, sp_p, n, nb);
    k3_finalize<<<n / 64, 256, 0, stream>>>(diag, se_p, sp_p, cnt_g, acc, counter, out, n, nb);
}

// Round 13
// 99.077 us; speedup vs baseline: 1.0190x; 1.0190x over previous
//
#include <hip/hip_runtime.h>
#include <hip/hip_bf16.h>

using bf16 = __hip_bfloat16;
typedef __attribute__((ext_vector_type(8))) short frag_ab;   // 8 bf16
typedef __attribute__((ext_vector_type(4))) float frag_cd;   // 4 fp32

constexpr float TEMP   = 0.07f;
constexpr float INVT   = 1.0f / TEMP;                 // fixed logsumexp shift
constexpr float THRESH = 0.1f;
constexpr float EPS    = 1e-8f;
constexpr float LOG2E  = 1.4426950408889634f;
constexpr float C1     = LOG2E / TEMP;                // exp((s-1)/T) = exp2(s*C1 - C1)

constexpr int D      = 128;
constexpr int SPLITS = 16;    // column splits -> grid (64,16) = 1024 blocks (champion cfg)
constexpr int TI     = 128;   // rows per block (4 waves x 32 rows)
constexpr int TJ     = 64;    // cols per LDS tile

__device__ __forceinline__ frag_cd mfma16(frag_ab a, frag_ab b, frag_cd c) {
    return __builtin_amdgcn_mfma_f32_16x16x32_bf16(a, b, c, 0, 0, 0);
}

// async global->LDS DMA, 16B per lane, LDS dest = wave-uniform base + lane*16
__device__ __forceinline__ void async_copy16(const bf16* gp, bf16* lp) {
    __builtin_amdgcn_global_load_lds(
        (__attribute__((address_space(1))) void*)(gp),
        (__attribute__((address_space(3))) void*)(lp), 16, 0, 0);
}

// ------- kernel 1: row-normalize -> bf16, diagonal dot, LABEL-ONLY positive count -------
// cnt_i = #{j : |l_i - l_j| < THRESH} - 1 is label-only (R12-verified exact, absmax 0).
// Moving it here deletes 1 VALU/elem + butterfly + a 2 MB partial from k2's hot loop.
__global__ __launch_bounds__(256) void k1_normalize(
    const float* __restrict__ f, const float* __restrict__ lab,
    bf16* __restrict__ fn, float* __restrict__ diag,
    float* __restrict__ cnt_g, float* __restrict__ acc,
    unsigned* __restrict__ counter, int n)
{
    if (blockIdx.x == 0 && threadIdx.x == 0) { acc[0] = 0.f; counter[0] = 0u; }
    const int row  = blockIdx.x * 4 + (threadIdx.x >> 6);
    const int lane = threadIdx.x & 63;
    float2 v = ((const float2*)(f + (size_t)row * D))[lane];
    float ss = v.x * v.x + v.y * v.y;
    #pragma unroll
    for (int m = 32; m >= 1; m >>= 1) ss += __shfl_xor(ss, m, 64);
    const float inv = 1.0f / fmaxf(sqrtf(ss), EPS);
    __hip_bfloat162 o;
    o.x = __float2bfloat16(v.x * inv);
    o.y = __float2bfloat16(v.y * inv);
    ((__hip_bfloat162*)(fn + (size_t)row * D))[lane] = o;
    // diagonal raw dot of the bf16-rounded row (matches MFMA s_ii to ~1e-6)
    const float a = __bfloat162float(o.x), b = __bfloat162float(o.y);
    float p = a * a + b * b;
    #pragma unroll
    for (int m = 32; m >= 1; m >>= 1) p += __shfl_xor(p, m, 64);
    if (lane == 0) diag[row] = p;

    // label-only count (32 float4-iters/lane; lab array is L1/L2-resident)
    const float li = lab[row];
    float c = 0.f;
    const int it = n >> 8;                   // n/256 float4-iters per lane
    for (int k = 0; k < it; ++k) {
        const float4 lv = ((const float4*)lab)[lane + 64 * k];
        c += (fabsf(lv.x - li) < THRESH) ? 1.f : 0.f;
        c += (fabsf(lv.y - li) < THRESH) ? 1.f : 0.f;
        c += (fabsf(lv.z - li) < THRESH) ? 1.f : 0.f;
        c += (fabsf(lv.w - li) < THRESH) ? 1.f : 0.f;
    }
    #pragma unroll
    for (int m = 32; m >= 1; m >>= 1) c += __shfl_xor(c, m, 64);
    if (lane == 0) cnt_g[row] = c - 1.0f;    // exclude self (exact f32 integer sums)
}

// ---------------- kernel 2: fused sim + masked reductions (R5 champion structure) ----------------
// TJ=64, SPLITS=16, double-buffered swizzled LDS, ONE barrier/tile, convoy stagger,
// global_load_lds DMA staging (m173 pre-swizzled-source, R3/R5-verified). The ONLY
// change vs the measured 93.64 champion: cnt accumulation removed (label-only, k1) —
// strictly less VALU (1 op/elem), fewer shuffles, fewer stores, ~8 fewer VGPRs.
//
// SYMMETRIC-ARC POST-MORTEM (R6-R12, abandoned): triangular tiling halves MFMA/exp2
// but 8-sub blocks amortize DMA-wait/prologue/epilogue over 1/4 the compute of this
// kernel's 32-sub blocks; 6 delivery mechanisms all landed k2 >= ~38us vs this ~37us.
// LAUNCH-BOUNDS LAW (R0/R2/R4/R7 measured): arch-VGPR cap = 256/min_waves.
//   (256,3)->85 cap: champion ran 84 regs no-spill; this variant is leaner. DO NOT RAISE.
__global__ __launch_bounds__(256, 3) void k2_main(
    const bf16* __restrict__ fn, const float* __restrict__ lab,
    float* __restrict__ se_p, float* __restrict__ sp_p, int n)
{
    __shared__ float lab_s[512];             // cps = 8192/16
    __shared__ bf16  colbuf[2][TJ * D];      // col c, slot s holds source chunk s^(c&15)

    const int tid  = threadIdx.x;
    const int wave = tid >> 6;
    const int lane = tid & 63;
    const int quad = lane >> 4;
    const int l15  = lane & 15;

    const int cps    = n / SPLITS;        // 512
    const int cbase0 = blockIdx.y * cps;
    const int row_base = blockIdx.x * TI + wave * 32;

    for (int i = tid; i < cps; i += 256) lab_s[i] = lab[cbase0 + i];

    // A fragments: set s covers rows row_base + s*16 + l15, k = kb*32 + quad*8 + j
    frag_ab afr[2][4];
    #pragma unroll
    for (int s = 0; s < 2; ++s) {
        const bf16* ap = fn + (size_t)(row_base + s * 16 + l15) * D + quad * 8;
        #pragma unroll
        for (int kb = 0; kb < 4; ++kb) afr[s][kb] = *(const frag_ab*)(ap + kb * 32);
    }
    float li[2][4];
    #pragma unroll
    for (int s = 0; s < 2; ++s)
        #pragma unroll
        for (int r = 0; r < 4; ++r)
            li[s][r] = lab[row_base + s * 16 + quad * 4 + r];

    float se[2][4] = {}, sp[2][4] = {};

    // ---- DMA staging geometry: 4 issues/wave cover the 16KB tile ----
    // issue i, lane l: LDS byte = wave*4096 + i*1024 + l*16
    //   -> col c = wave*16 + i*4 + (l>>4), slot = l&15, source chunk k = l15 ^ (c&15)
    int coloff[4];                        // bf16-unit src offset within the tile
    #pragma unroll
    for (int i = 0; i < 4; ++i) {
        const int ci = wave * 16 + i * 4 + (lane >> 4);
        const int ki = l15 ^ (i * 4 + (lane >> 4));
        coloff[i] = ci * D + ki * 8;
    }
    bf16* lbase[2] = { &colbuf[0][wave * 2048], &colbuf[1][wave * 2048] };

    const int ntiles = cps / TJ;  // 8
    const int jt0 = (blockIdx.x + blockIdx.y) & (ntiles - 1);  // convoy stagger

    // prologue: DMA tile jt0 -> buf[0]; barrier drains vmcnt (and covers lab_s)
    {
        const bf16* gt = fn + (size_t)(cbase0 + jt0 * TJ) * D;
        #pragma unroll
        for (int i = 0; i < 4; ++i)
            async_copy16(gt + coloff[i], lbase[0] + i * 512);
    }
    __syncthreads();

    for (int t = 0; t < ntiles; ++t) {
        const int cur = t & 1;
        const int jt  = (jt0 + t) & (ntiles - 1);
        // issue next tile's DMA NOW — lands in buf[cur^1] during this compute phase
        if (t + 1 < ntiles) {
            const int jn = (jt0 + t + 1) & (ntiles - 1);
            const bf16* gt = fn + (size_t)(cbase0 + jn * TJ) * D;
            #pragma unroll
            for (int i = 0; i < 4; ++i)
                async_copy16(gt + coloff[i], lbase[cur ^ 1] + i * 512);
        }

        #pragma unroll
        for (int sub = 0; sub < 4; ++sub) {
            const int c = sub * 16 + l15;          // column within tile
            frag_ab b[4];
            #pragma unroll
            for (int kb = 0; kb < 4; ++kb)
                b[kb] = *(const frag_ab*)(&colbuf[cur][(size_t)c * D + (((quad + 4 * kb) ^ l15) * 8)]);
            frag_cd a0 = {0.f, 0.f, 0.f, 0.f}, a1 = {0.f, 0.f, 0.f, 0.f};
            #pragma unroll
            for (int kb = 0; kb < 4; ++kb) {
                a0 = mfma16(afr[0][kb], b[kb], a0);
                a1 = mfma16(afr[1][kb], b[kb], a1);
            }
            const float lj = lab_s[jt * TJ + c];
            #pragma unroll
            for (int s = 0; s < 2; ++s) {
                const frag_cd& acc = s ? a1 : a0;
                #pragma unroll
                for (int r = 0; r < 4; ++r) {
                    const float sv = acc[r];                      // raw dot (cosine)
                    const float e  = __builtin_amdgcn_exp2f(__builtin_fmaf(sv, C1, -C1));
                    const float pm = (fabsf(li[s][r] - lj) < THRESH) ? 1.0f : 0.0f;
                    se[s][r] += e;
                    sp[s][r]  = __builtin_fmaf(pm, sv, sp[s][r]); // raw dots; 1/T in k3
                }
            }
        }

        // compiler emits s_waitcnt vmcnt(0) before s_barrier: buf[cur^1] fully landed
        // for t+1, and all waves done reading buf[cur] before its overwrite at t+1.
        __syncthreads();
    }

    // reduce across the 16 lanes of each quad-group (same rows, cols mod 16)
    #pragma unroll
    for (int s = 0; s < 2; ++s)
        #pragma unroll
        for (int r = 0; r < 4; ++r) {
            #pragma unroll
            for (int m = 1; m < 16; m <<= 1) {
                se[s][r] += __shfl_xor(se[s][r], m, 64);
                sp[s][r] += __shfl_xor(sp[s][r], m, 64);
            }
        }
    if (l15 == 0) {
        #pragma unroll
        for (int s = 0; s < 2; ++s)
            #pragma unroll
            for (int r = 0; r < 4; ++r) {
                const int i = row_base + s * 16 + quad * 4 + r;
                se_p[(size_t)blockIdx.y * n + i] = se[s][r];
                sp_p[(size_t)blockIdx.y * n + i] = sp[s][r];
            }
    }
}

// ------- kernel 3: per-row finalize + grid reduction (last-block pattern) -------
__global__ __launch_bounds__(256) void k3_finalize(
    const float* __restrict__ diag, const float* __restrict__ se_p,
    const float* __restrict__ sp_p, const float* __restrict__ cnt_g,
    float* __restrict__ acc, unsigned* __restrict__ counter,
    float* __restrict__ out, int n)
{
    const int row = blockIdx.x * 256 + threadIdx.x;
    float se = 0.f, sp = 0.f;
    #pragma unroll
    for (int s = 0; s < SPLITS; ++s) {
        se += se_p[(size_t)s * n + row];
        sp += sp_p[(size_t)s * n + row];
    }
    const float s_ii = diag[row];
    se -= __builtin_amdgcn_exp2f(__builtin_fmaf(s_ii, C1, -C1));
    sp -= s_ii;
    const float cnt = cnt_g[row];            // label-only count, already excludes self
    float loss = INVT + __logf(se) - (sp * INVT) / fmaxf(cnt, 1.0f);

    // block reduce
    #pragma unroll
    for (int m = 32; m >= 1; m >>= 1) loss += __shfl_xor(loss, m, 64);
    __shared__ float wsum[4];
    if ((threadIdx.x & 63) == 0) wsum[threadIdx.x >> 6] = loss;
    __syncthreads();
    if (threadIdx.x == 0) {
        const float bs = wsum[0] + wsum[1] + wsum[2] + wsum[3];
        atomicAdd(acc, bs);
        __threadfence();
        const unsigned old = atomicAdd(counter, 1u);
        if (old == gridDim.x - 1) {
            const float total = atomicAdd(acc, 0.0f);  // atomic load, same-address order
            out[0] = total / (float)n;
        }
    }
}

extern "C" void kernel_launch(void* const* d_in, const int* in_sizes, int n_in,
                              void* d_out, int out_size, void* d_ws, size_t ws_size,
                              hipStream_t stream) {
    const float* feat = (const float*)d_in[0];
    const float* lab  = (const float*)d_in[1];
    const int n = in_sizes[1];              // 8192
    float* out = (float*)d_out;

    // ws: fn (n*D bf16 = 2MB) | diag (n f32) | se_p | sp_p (each SPLITS*n f32 = 512KB)
    //     | cnt_g (n f32) | acc | counter
    char* ws = (char*)d_ws;
    bf16* fn = (bf16*)ws;
    size_t off = (size_t)n * D * sizeof(bf16);
    float* diag  = (float*)(ws + off); off += (size_t)n * sizeof(float);
    float* se_p  = (float*)(ws + off); off += (size_t)SPLITS * n * sizeof(float);
    float* sp_p  = (float*)(ws + off); off += (size_t)SPLITS * n * sizeof(float);
    float* cnt_g = (float*)(ws + off); off += (size_t)n * sizeof(float);
    float* acc   = (float*)(ws + off); off += sizeof(float);
    unsigned* counter = (unsigned*)(ws + off);

    k1_normalize<<<n / 4, 256, 0, stream>>>(feat, lab, fn, diag, cnt_g, acc, counter, n);
    dim3 g2(n / TI, SPLITS);
    k2_main<<<g2, 256, 0, stream>>>(fn, lab, se_p, sp_p, n);
    k3_finalize<<<n / 256, 256, 0, stream>>>(diag, se_p, sp_p, cnt_g, acc, counter, out, n);
}

// Round 14
// 93.505 us; speedup vs baseline: 1.0797x; 1.0596x over previous
//
#include <hip/hip_runtime.h>
#include <hip/hip_bf16.h>

using bf16 = __hip_bfloat16;
typedef __attribute__((ext_vector_type(8))) short frag_ab;   // 8 bf16
typedef __attribute__((ext_vector_type(4))) float frag_cd;   // 4 fp32

constexpr float TEMP   = 0.07f;
constexpr float INVT   = 1.0f / TEMP;                 // fixed logsumexp shift
constexpr float THRESH = 0.1f;
constexpr float EPS    = 1e-8f;
constexpr float LOG2E  = 1.4426950408889634f;
constexpr float C1     = LOG2E / TEMP;                // exp((s-1)/T) = exp2(s*C1 - C1)

constexpr int D      = 128;
constexpr int SPLITS = 16;    // column splits -> grid (64,16) = 1024 blocks (champion cfg)
constexpr int TI     = 128;   // rows per block (4 waves x 32 rows)
constexpr int TJ     = 64;    // cols per LDS tile

__device__ __forceinline__ frag_cd mfma16(frag_ab a, frag_ab b, frag_cd c) {
    return __builtin_amdgcn_mfma_f32_16x16x32_bf16(a, b, c, 0, 0, 0);
}

// async global->LDS DMA, 16B per lane, LDS dest = wave-uniform base + lane*16
__device__ __forceinline__ void async_copy16(const bf16* gp, bf16* lp) {
    __builtin_amdgcn_global_load_lds(
        (__attribute__((address_space(1))) void*)(gp),
        (__attribute__((address_space(3))) void*)(lp), 16, 0, 0);
}

// ------- kernel 1: row-normalize -> bf16, diagonal dot, zero-init reduction cells -------
__global__ __launch_bounds__(256) void k1_normalize(
    const float* __restrict__ f, bf16* __restrict__ fn,
    float* __restrict__ diag, float* __restrict__ acc,
    unsigned* __restrict__ counter, int n)
{
    if (blockIdx.x == 0 && threadIdx.x == 0) { acc[0] = 0.f; counter[0] = 0u; }
    const int row  = blockIdx.x * 4 + (threadIdx.x >> 6);
    const int lane = threadIdx.x & 63;
    float2 v = ((const float2*)(f + (size_t)row * D))[lane];
    float ss = v.x * v.x + v.y * v.y;
    #pragma unroll
    for (int m = 32; m >= 1; m >>= 1) ss += __shfl_xor(ss, m, 64);
    const float inv = 1.0f / fmaxf(sqrtf(ss), EPS);
    __hip_bfloat162 o;
    o.x = __float2bfloat16(v.x * inv);
    o.y = __float2bfloat16(v.y * inv);
    ((__hip_bfloat162*)(fn + (size_t)row * D))[lane] = o;
    // diagonal raw dot of the bf16-rounded row (matches MFMA s_ii to ~1e-6)
    const float a = __bfloat162float(o.x), b = __bfloat162float(o.y);
    float p = a * a + b * b;
    #pragma unroll
    for (int m = 32; m >= 1; m >>= 1) p += __shfl_xor(p, m, 64);
    if (lane == 0) diag[row] = p;
}

// ---------------- kernel 2: fused sim + masked reductions ----------------
// R5 CHAMPION — measured 93.64 us total, byte-exact revert (R13 falsification branch).
// TJ=64, SPLITS=16, double-buffered swizzled LDS, ONE barrier/tile, convoy stagger,
// global_load_lds DMA staging (m173 pre-swizzled-source pattern: LDS dest linear per
// HW requirement, swizzle produced by pre-permuting each lane's GLOBAL source chunk).
//
// SESSION LEDGER (why this exact shape):
//  - no-LDS streaming (R1): 69us — LDS sharing is load-bearing (4x L2 traffic cut).
//  - TJ=32/SPLITS=32 (R2/R3): worse amortization per barrier/prologue.
//  - symmetric triangular tiling (R6-R12): halves MFMA but 6 delivery mechanisms all
//    landed k2 >= 38us vs this ~37us (per-block fixed costs at 1/4 the compute).
//  - cnt hoisted to label-only k1 (R13): O(n^2) label scan costs more than cnt-in-k2.
// LAUNCH-BOUNDS LAW (R0/R2/R4 measured): arch-VGPR cap = 256/min_waves.
//   (256,3) -> 85 cap (84 used, no spill). (256,4)->64 and (256,6)->40 SPILL. DO NOT RAISE.
__global__ __launch_bounds__(256, 3) void k2_main(
    const bf16* __restrict__ fn, const float* __restrict__ lab,
    float* __restrict__ se_p, float* __restrict__ sp_p,
    float* __restrict__ cnt_p, int n)
{
    __shared__ float lab_s[512];             // cps = 8192/16
    __shared__ bf16  colbuf[2][TJ * D];      // col c, slot s holds source chunk s^(c&15)

    const int tid  = threadIdx.x;
    const int wave = tid >> 6;
    const int lane = tid & 63;
    const int quad = lane >> 4;
    const int l15  = lane & 15;

    const int cps    = n / SPLITS;        // 512
    const int cbase0 = blockIdx.y * cps;
    const int row_base = blockIdx.x * TI + wave * 32;

    for (int i = tid; i < cps; i += 256) lab_s[i] = lab[cbase0 + i];

    // A fragments: set s covers rows row_base + s*16 + l15, k = kb*32 + quad*8 + j
    frag_ab afr[2][4];
    #pragma unroll
    for (int s = 0; s < 2; ++s) {
        const bf16* ap = fn + (size_t)(row_base + s * 16 + l15) * D + quad * 8;
        #pragma unroll
        for (int kb = 0; kb < 4; ++kb) afr[s][kb] = *(const frag_ab*)(ap + kb * 32);
    }
    float li[2][4];
    #pragma unroll
    for (int s = 0; s < 2; ++s)
        #pragma unroll
        for (int r = 0; r < 4; ++r)
            li[s][r] = lab[row_base + s * 16 + quad * 4 + r];

    float se[2][4] = {}, sp[2][4] = {}, cnt[2][4] = {};

    // ---- DMA staging geometry: 4 issues/wave cover the 16KB tile ----
    // issue i, lane l: LDS byte = wave*4096 + i*1024 + l*16
    //   -> col c = wave*16 + i*4 + (l>>4), slot = l&15, source chunk k = l15 ^ (c&15)
    // (c&15 = i*4 + (l>>4) since wave*16 ≡ 0 mod 16)
    int coloff[4];                        // bf16-unit src offset within the tile
    #pragma unroll
    for (int i = 0; i < 4; ++i) {
        const int ci = wave * 16 + i * 4 + (lane >> 4);
        const int ki = l15 ^ (i * 4 + (lane >> 4));
        coloff[i] = ci * D + ki * 8;
    }
    bf16* lbase[2] = { &colbuf[0][wave * 2048], &colbuf[1][wave * 2048] };

    const int ntiles = cps / TJ;  // 8
    const int jt0 = (blockIdx.x + blockIdx.y) & (ntiles - 1);  // convoy stagger

    // prologue: DMA tile jt0 -> buf[0]; barrier drains vmcnt (and covers lab_s)
    {
        const bf16* gt = fn + (size_t)(cbase0 + jt0 * TJ) * D;
        #pragma unroll
        for (int i = 0; i < 4; ++i)
            async_copy16(gt + coloff[i], lbase[0] + i * 512);
    }
    __syncthreads();

    for (int t = 0; t < ntiles; ++t) {
        const int cur = t & 1;
        const int jt  = (jt0 + t) & (ntiles - 1);
        // issue next tile's DMA NOW — lands in buf[cur^1] during this compute phase
        if (t + 1 < ntiles) {
            const int jn = (jt0 + t + 1) & (ntiles - 1);
            const bf16* gt = fn + (size_t)(cbase0 + jn * TJ) * D;
            #pragma unroll
            for (int i = 0; i < 4; ++i)
                async_copy16(gt + coloff[i], lbase[cur ^ 1] + i * 512);
        }

        #pragma unroll
        for (int sub = 0; sub < 4; ++sub) {
            const int c = sub * 16 + l15;          // column within tile
            frag_ab b[4];
            #pragma unroll
            for (int kb = 0; kb < 4; ++kb)
                b[kb] = *(const frag_ab*)(&colbuf[cur][(size_t)c * D + (((quad + 4 * kb) ^ l15) * 8)]);
            frag_cd a0 = {0.f, 0.f, 0.f, 0.f}, a1 = {0.f, 0.f, 0.f, 0.f};
            #pragma unroll
            for (int kb = 0; kb < 4; ++kb) {
                a0 = mfma16(afr[0][kb], b[kb], a0);
                a1 = mfma16(afr[1][kb], b[kb], a1);
            }
            const float lj = lab_s[jt * TJ + c];
            #pragma unroll
            for (int s = 0; s < 2; ++s) {
                const frag_cd& acc = s ? a1 : a0;
                #pragma unroll
                for (int r = 0; r < 4; ++r) {
                    const float sv = acc[r];                      // raw dot (cosine)
                    const float e  = __builtin_amdgcn_exp2f(__builtin_fmaf(sv, C1, -C1));
                    const float pm = (fabsf(li[s][r] - lj) < THRESH) ? 1.0f : 0.0f;
                    se[s][r]  += e;
                    sp[s][r]   = __builtin_fmaf(pm, sv, sp[s][r]); // raw dots; 1/T in k3
                    cnt[s][r] += pm;
                }
            }
        }

        // compiler emits s_waitcnt vmcnt(0) before s_barrier: buf[cur^1] is fully
        // landed for t+1, and every wave is done reading buf[cur] before its
        // overwrite gets issued at the top of t+1.
        __syncthreads();
    }

    // reduce across the 16 lanes of each quad-group (same rows, cols mod 16)
    #pragma unroll
    for (int s = 0; s < 2; ++s)
        #pragma unroll
        for (int r = 0; r < 4; ++r) {
            #pragma unroll
            for (int m = 1; m < 16; m <<= 1) {
                se[s][r]  += __shfl_xor(se[s][r],  m, 64);
                sp[s][r]  += __shfl_xor(sp[s][r],  m, 64);
                cnt[s][r] += __shfl_xor(cnt[s][r], m, 64);
            }
        }
    if (l15 == 0) {
        #pragma unroll
        for (int s = 0; s < 2; ++s)
            #pragma unroll
            for (int r = 0; r < 4; ++r) {
                const int i = row_base + s * 16 + quad * 4 + r;
                se_p[(size_t)blockIdx.y * n + i]  = se[s][r];
                sp_p[(size_t)blockIdx.y * n + i]  = sp[s][r];
                cnt_p[(size_t)blockIdx.y * n + i] = cnt[s][r];
            }
    }
}

// ------- kernel 3: per-row finalize + grid reduction (last-block pattern) -------
__global__ __launch_bounds__(256) void k3_finalize(
    const float* __restrict__ diag, const float* __restrict__ se_p,
    const float* __restrict__ sp_p, const float* __restrict__ cnt_p,
    float* __restrict__ acc, unsigned* __restrict__ counter,
    float* __restrict__ out, int n)
{
    const int row = blockIdx.x * 256 + threadIdx.x;
    float se = 0.f, sp = 0.f, cnt = 0.f;
    #pragma unroll
    for (int s = 0; s < SPLITS; ++s) {
        se  += se_p[(size_t)s * n + row];
        sp  += sp_p[(size_t)s * n + row];
        cnt += cnt_p[(size_t)s * n + row];
    }
    const float s_ii = diag[row];
    se  -= __builtin_amdgcn_exp2f(__builtin_fmaf(s_ii, C1, -C1));
    sp  -= s_ii;
    cnt -= 1.0f;
    float loss = INVT + __logf(se) - (sp * INVT) / fmaxf(cnt, 1.0f);

    // block reduce
    #pragma unroll
    for (int m = 32; m >= 1; m >>= 1) loss += __shfl_xor(loss, m, 64);
    __shared__ float wsum[4];
    if ((threadIdx.x & 63) == 0) wsum[threadIdx.x >> 6] = loss;
    __syncthreads();
    if (threadIdx.x == 0) {
        const float bs = wsum[0] + wsum[1] + wsum[2] + wsum[3];
        atomicAdd(acc, bs);
        __threadfence();
        const unsigned old = atomicAdd(counter, 1u);
        if (old == gridDim.x - 1) {
            const float total = atomicAdd(acc, 0.0f);  // atomic load, same-address order
            out[0] = total / (float)n;
        }
    }
}

extern "C" void kernel_launch(void* const* d_in, const int* in_sizes, int n_in,
                              void* d_out, int out_size, void* d_ws, size_t ws_size,
                              hipStream_t stream) {
    const float* feat = (const float*)d_in[0];
    const float* lab  = (const float*)d_in[1];
    const int n = in_sizes[1];              // 8192
    float* out = (float*)d_out;

    // ws: fn (n*D bf16 = 2MB) | diag | se_p | sp_p | cnt_p (each SPLITS*n f32) | acc | counter
    char* ws = (char*)d_ws;
    bf16* fn = (bf16*)ws;
    size_t off = (size_t)n * D * sizeof(bf16);
    float* diag  = (float*)(ws + off); off += (size_t)n * sizeof(float);
    float* se_p  = (float*)(ws + off); off += (size_t)SPLITS * n * sizeof(float);
    float* sp_p  = (float*)(ws + off); off += (size_t)SPLITS * n * sizeof(float);
    float* cnt_p = (float*)(ws + off); off += (size_t)SPLITS * n * sizeof(float);
    float* acc   = (float*)(ws + off); off += sizeof(float);
    unsigned* counter = (unsigned*)(ws + off);

    k1_normalize<<<n / 4, 256, 0, stream>>>(feat, fn, diag, acc, counter, n);
    dim3 g2(n / TI, SPLITS);
    k2_main<<<g2, 256, 0, stream>>>(fn, lab, se_p, sp_p, cnt_p, n);
    k3_finalize<<<n / 256, 256, 0, stream>>>(diag, se_p, sp_p, cnt_p, acc, counter, out, n);
}